// Round 4
// baseline (1448.923 us; speedup 1.0000x reference)
//
#include <hip/hip_runtime.h>

// CSR-gather design (no float atomics):
//   1. count_kernel:  cnt[n] = #events per node          (int atomics, 400 KB)
//   2. scan (3 kernels): offsets = exclusive_scan(cnt)   (two-level LDS scan)
//   3. bucket_kernel: perm[offsets[n] + k] = event idx   (int atomics on cursor)
//   4. gather_kernel: one wave per node sums its rows, divides, stores.
//
// Gather v2: lane-parallel perm fetch + shfl broadcast + 4-way unrolled
// independent row loads. Removes the serial perm->row dependent chain that
// capped per-wave MLP at ~1KB/2-latencies (theory: latency-bound, not BW).
//
// d_out layout (float32): [N*D mean | N last_ts | N counts]
// Timestamps sorted ascending => last ts per node = timestamps[max event idx].
// Every output element is written by gather_kernel => no d_out memset needed.

#define SCAN_BLOCK 256
#define L2_BLOCK   512   // single-block second-level scan capacity

__global__ void count_kernel(const int* __restrict__ node_ids,
                             int* __restrict__ cnt, int B) {
    int e = blockIdx.x * blockDim.x + threadIdx.x;
    if (e < B) atomicAdd(&cnt[node_ids[e]], 1);
}

// Per-block exclusive scan of cnt -> excl, block totals -> blockSums.
__global__ void scan_blocks(const int* __restrict__ cnt,
                            int* __restrict__ excl,
                            int* __restrict__ blockSums, int N) {
    __shared__ int s[SCAN_BLOCK];
    int gid = blockIdx.x * SCAN_BLOCK + threadIdx.x;
    int v = (gid < N) ? cnt[gid] : 0;
    s[threadIdx.x] = v;
    __syncthreads();
    for (int off = 1; off < SCAN_BLOCK; off <<= 1) {
        int t = (threadIdx.x >= off) ? s[threadIdx.x - off] : 0;
        __syncthreads();
        s[threadIdx.x] += t;
        __syncthreads();
    }
    int incl = s[threadIdx.x];
    if (gid < N) excl[gid] = incl - v;
    if (threadIdx.x == SCAN_BLOCK - 1) blockSums[blockIdx.x] = incl;
}

// Single-block exclusive scan of blockSums (nb <= L2_BLOCK).
__global__ void scan_block_sums(int* __restrict__ blockSums, int nb) {
    __shared__ int s[L2_BLOCK];
    int v = (threadIdx.x < nb) ? blockSums[threadIdx.x] : 0;
    s[threadIdx.x] = v;
    __syncthreads();
    for (int off = 1; off < L2_BLOCK; off <<= 1) {
        int t = (threadIdx.x >= off) ? s[threadIdx.x - off] : 0;
        __syncthreads();
        s[threadIdx.x] += t;
        __syncthreads();
    }
    if (threadIdx.x < nb) blockSums[threadIdx.x] = s[threadIdx.x] - v;
}

// excl += blockSums[block]; cursor = excl (mutable copy for bucketing).
__global__ void add_offsets(int* __restrict__ excl,
                            const int* __restrict__ blockSums,
                            int* __restrict__ cursor, int N) {
    int gid = blockIdx.x * SCAN_BLOCK + threadIdx.x;
    if (gid < N) {
        int o = excl[gid] + blockSums[blockIdx.x];
        excl[gid] = o;
        cursor[gid] = o;
    }
}

__global__ void bucket_kernel(const int* __restrict__ node_ids,
                              int* __restrict__ cursor,
                              int* __restrict__ perm, int B) {
    int e = blockIdx.x * blockDim.x + threadIdx.x;
    if (e < B) {
        int pos = atomicAdd(&cursor[node_ids[e]], 1);
        perm[pos] = e;
    }
}

// One 64-lane wave per node. Lane l owns columns [4l, 4l+4).
// v2: (a) perm indices fetched lane-parallel (one coalesced load covers the
// whole node's index list), broadcast via __shfl; (b) row loads unrolled
// 4-wide with independent addresses -> 4KB in flight per wave; (c) last_e
// computed as lane-local max + butterfly reduce (off the critical path).
__global__ void gather_kernel(const int* __restrict__ perm,
                              const int* __restrict__ offsets,
                              const int* __restrict__ cnt,
                              const float* __restrict__ messages,
                              const float* __restrict__ timestamps,
                              float* __restrict__ mean,     // [N, D]
                              float* __restrict__ last_ts,  // [N]
                              float* __restrict__ counts,   // [N]
                              int N, int D) {
    int wave = (blockIdx.x * blockDim.x + threadIdx.x) >> 6;
    int lane = threadIdx.x & 63;
    if (wave >= N) return;

    int start = offsets[wave];
    int c = cnt[wave];

    const float* mbase = messages + (size_t)(lane * 4);
    float4 acc = make_float4(0.f, 0.f, 0.f, 0.f);
    int last_e = -1;

    for (int base = 0; base < c; base += 64) {
        int n = min(c - base, 64);
        // One coalesced transaction fetches up to 64 event indices.
        int e_lane = (lane < n) ? perm[start + base + lane] : -1;
        last_e = max(last_e, e_lane);

        int i = 0;
        for (; i + 4 <= n; i += 4) {
            int e0 = __shfl(e_lane, i);
            int e1 = __shfl(e_lane, i + 1);
            int e2 = __shfl(e_lane, i + 2);
            int e3 = __shfl(e_lane, i + 3);
            float4 m0 = *reinterpret_cast<const float4*>(mbase + (size_t)e0 * D);
            float4 m1 = *reinterpret_cast<const float4*>(mbase + (size_t)e1 * D);
            float4 m2 = *reinterpret_cast<const float4*>(mbase + (size_t)e2 * D);
            float4 m3 = *reinterpret_cast<const float4*>(mbase + (size_t)e3 * D);
            acc.x += (m0.x + m1.x) + (m2.x + m3.x);
            acc.y += (m0.y + m1.y) + (m2.y + m3.y);
            acc.z += (m0.z + m1.z) + (m2.z + m3.z);
            acc.w += (m0.w + m1.w) + (m2.w + m3.w);
        }
        for (; i < n; ++i) {
            int e = __shfl(e_lane, i);
            float4 m = *reinterpret_cast<const float4*>(mbase + (size_t)e * D);
            acc.x += m.x; acc.y += m.y; acc.z += m.z; acc.w += m.w;
        }
    }

    // Wave-wide max of last_e (6-step butterfly).
    #pragma unroll
    for (int off = 32; off > 0; off >>= 1)
        last_e = max(last_e, __shfl_xor(last_e, off));

    float inv = 1.0f / fmaxf((float)c, 1.0f);
    acc.x *= inv; acc.y *= inv; acc.z *= inv; acc.w *= inv;
    *reinterpret_cast<float4*>(mean + (size_t)wave * D + lane * 4) = acc;

    if (lane == 0) {
        counts[wave] = (float)c;
        last_ts[wave] = (c > 0) ? timestamps[last_e] : 0.0f;
    }
}

extern "C" void kernel_launch(void* const* d_in, const int* in_sizes, int n_in,
                              void* d_out, int out_size, void* d_ws, size_t ws_size,
                              hipStream_t stream) {
    const int*   node_ids   = (const int*)  d_in[0];
    const float* messages   = (const float*)d_in[1];
    const float* timestamps = (const float*)d_in[2];

    const int B = in_sizes[0];
    const int D = in_sizes[1] / B;          // 256
    const int N = out_size / (D + 2);       // out = N*D + N + N floats

    float* out     = (float*)d_out;
    float* mean    = out;                    // [N, D]
    float* last_ts = out + (size_t)N * D;    // [N]
    float* counts  = last_ts + N;            // [N]

    // Workspace layout (ints): cnt[N] | excl[N] | cursor[N] | blockSums[nb] | perm[B]
    const int nb = (N + SCAN_BLOCK - 1) / SCAN_BLOCK;   // 391 for N=100K
    int* cnt       = (int*)d_ws;
    int* excl      = cnt + N;
    int* cursor    = excl + N;
    int* blockSums = cursor + N;
    int* perm      = blockSums + nb;

    // Only cnt needs zero-init (ws is poisoned to 0xAA each launch).
    hipMemsetAsync(cnt, 0, (size_t)N * sizeof(int), stream);

    int gridB = (B + 255) / 256;
    count_kernel<<<gridB, 256, 0, stream>>>(node_ids, cnt, B);

    scan_blocks<<<nb, SCAN_BLOCK, 0, stream>>>(cnt, excl, blockSums, N);
    scan_block_sums<<<1, L2_BLOCK, 0, stream>>>(blockSums, nb);
    add_offsets<<<nb, SCAN_BLOCK, 0, stream>>>(excl, blockSums, cursor, N);

    bucket_kernel<<<gridB, 256, 0, stream>>>(node_ids, cursor, perm, B);

    // Gather: 4 waves per 256-thread block, one wave per node.
    int gridG = (N + 3) / 4;
    gather_kernel<<<gridG, 256, 0, stream>>>(perm, excl, cnt, messages, timestamps,
                                             mean, last_ts, counts, N, D);
}